// Round 4
// baseline (566.632 us; speedup 1.0000x reference)
//
#include <hip/hip_runtime.h>

typedef float    f32x4 __attribute__((ext_vector_type(4)));
typedef short    s16x8 __attribute__((ext_vector_type(8)));
typedef unsigned u32x2 __attribute__((ext_vector_type(2)));

#define ND   64
#define DE   32
#define K1   160
#define K1P  168    // w1t row stride (ushort)
#define SP   104    // strip row stride: 96 data + 8 pad (208B, 2-way banks)
#define XWP  72     // xwin row stride (144B, 2-way banks)
#define K2P  72
#define KN   128
#define KNP  136
#define BKT  32     // nodes per bucket
#define EMASK 0x1FFFFFF

__device__ __forceinline__ ushort f2bf(float f) {
  unsigned u = __float_as_uint(f);
  return (ushort)((u + 0x7fffu + ((u >> 16) & 1u)) >> 16);  // RNE
}
__device__ __forceinline__ float relu_f(float v) { return v > 0.f ? v : 0.f; }
__device__ __forceinline__ unsigned cvtpk(float lo, float hi) {
  unsigned r;
  asm("v_cvt_pk_bf16_f32 %0, %1, %2" : "=v"(r) : "v"(lo), "v"(hi));
  return r;
}

// ---- B1: per-node degree histogram -----------------------------------------
__global__ void gc_hist(const int* __restrict__ eidx, float* __restrict__ deg, int E) {
  int i = blockIdx.x * blockDim.x + threadIdx.x;
  for (; i < E; i += gridDim.x * blockDim.x)
    atomicAdd(&deg[eidx[E + i]], 1.0f);
}

// ---- B2: bucket offsets (single block) -------------------------------------
__global__ void gc_prefix(const float* __restrict__ deg, int N, int NB,
                          int* __restrict__ offset, int* __restrict__ cursor) {
  __shared__ int cnt[2048];
  const int t = threadIdx.x;
  for (int b = t; b < NB; b += 256) {
    int s = 0, base = b * BKT;
    #pragma unroll
    for (int j = 0; j < BKT; ++j) {
      int node = base + j;
      s += (node < N) ? (int)deg[node] : 0;
    }
    cnt[b] = s;
  }
  __syncthreads();
  if (t < 64) {
    int running = 0;
    for (int base = 0; base < NB; base += 64) {
      int b = base + t;
      int v = (b < NB) ? cnt[b] : 0;
      int incl = v;
      #pragma unroll
      for (int d = 1; d < 64; d <<= 1) {
        int u = __shfl_up(incl, d);
        if (t >= d) incl += u;
      }
      if (b < NB) { int ex = running + incl - v; offset[b] = ex; cursor[b] = ex; }
      running += __shfl(incl, 63);
    }
    if (t == 0) offset[NB] = running;
  }
}

// ---- B3: place edge records into bucket order ------------------------------
__global__ void gc_place(const int* __restrict__ eidx, int* __restrict__ cursor,
                         int2* __restrict__ recs, int E) {
  int i = blockIdx.x * blockDim.x + threadIdx.x;
  for (; i < E; i += gridDim.x * blockDim.x) {
    int col = eidx[E + i];
    int row = eidx[i];
    int b = col >> 5;
    int pos = atomicAdd(&cursor[b], 1);
    recs[pos] = make_int2(row, ((col & 31) << 25) | i);
  }
}

// ---- B4: bucketed edge kernel: gather -> GEMM1 -> ReLU -> LDS-accumulate ---
__launch_bounds__(256, 3)
__global__ void gc_edge_b(const float* __restrict__ x,
                          const float* __restrict__ eattr,
                          const float* __restrict__ W1e, const float* __restrict__ b1e,
                          const int2* __restrict__ recs, const int* __restrict__ offset,
                          ushort* __restrict__ hsum, int N) {
  __shared__ ushort w1t[ND][K1P];        // W1e transposed [d][k]
  __shared__ ushort strip[4][16][SP];    // per-wave: 16 edges x (64 xrow + 32 attr)
  __shared__ ushort xwin[BKT][XWP];      // this bucket's x rows (bf16)
  __shared__ float  acc[BKT][ND];        // f32 accumulator

  const int t    = threadIdx.x;
  const int lane = t & 63;
  const int w    = t >> 6;
  const int l15  = lane & 15;
  const int lhi  = lane >> 4;
  const int k8   = lhi * 8;
  const int bkt  = blockIdx.x;
  const int node0 = bkt * BKT;

  for (int i = t; i < K1 * ND; i += 256) w1t[i & 63][i >> 6] = f2bf(W1e[i]);
  #pragma unroll
  for (int i = 0; i < 2; ++i) {           // xwin: 32 rows x 16 f32x4
    int c = t + i * 256;
    int r = c >> 4, p = c & 15;
    int node = node0 + r;
    f32x4 v = {0.f, 0.f, 0.f, 0.f};
    if (node < N) v = *(const f32x4*)(x + (size_t)node * ND + p * 4);
    u32x2 d = { cvtpk(v.x, v.y), cvtpk(v.z, v.w) };
    *(u32x2*)&xwin[r][p * 4] = d;
  }
  #pragma unroll
  for (int i = 0; i < 8; ++i) {           // zero acc
    int c = t + i * 256;
    acc[c >> 6][c & 63] = 0.f;
  }
  __syncthreads();

  float bias[4];
  #pragma unroll
  for (int n = 0; n < 4; ++n) bias[n] = b1e[n * 16 + l15];

  const int start = offset[bkt], end = offset[bkt + 1];
  const int nIter = (end - start + 63) >> 6;
  const int el = lane >> 2, part = lane & 3;

  for (int it = 0; it < nIter; ++it) {
    const int eBase = start + it * 64 + w * 16;
    int recx = 0, recy = 0;
    if (lane < 16) {
      int idx = eBase + lane;
      if (idx >= end) idx = end - 1;
      int2 r_ = recs[idx];
      recx = r_.x; recy = r_.y;
    }
    const int rowv  = __shfl(recx, el);
    const int eidA  = __shfl(recy, lane >> 3) & EMASK;
    const int eidB  = __shfl(recy, 8 + (lane >> 3)) & EMASK;
    const int myloc = __shfl(recy, l15) >> 25;

    const float* xr = x + (size_t)rowv * ND + part * 4;
    f32x4 vr[4];
    #pragma unroll
    for (int i = 0; i < 4; ++i) vr[i] = *(const f32x4*)(xr + i * 16);
    f32x4 va0 = *(const f32x4*)(eattr + (size_t)eidA * DE + (lane & 7) * 4);
    f32x4 va1 = *(const f32x4*)(eattr + (size_t)eidB * DE + (lane & 7) * 4);

    #pragma unroll
    for (int i = 0; i < 4; ++i) {
      u32x2 d = { cvtpk(vr[i].x, vr[i].y), cvtpk(vr[i].z, vr[i].w) };
      *(u32x2*)&strip[w][el][i * 16 + part * 4] = d;
    }
    { u32x2 d = { cvtpk(va0.x, va0.y), cvtpk(va0.z, va0.w) };
      *(u32x2*)&strip[w][lane >> 3][64 + (lane & 7) * 4] = d; }
    { u32x2 d = { cvtpk(va1.x, va1.y), cvtpk(va1.z, va1.w) };
      *(u32x2*)&strip[w][8 + (lane >> 3)][64 + (lane & 7) * 4] = d; }
    asm volatile("s_waitcnt lgkmcnt(0)" ::: "memory");

    // A-frags: k 0..63 = x[row] (strip), 64..127 = x[col] (xwin), 128..159 = attr
    s16x8 a0 = *(const s16x8*)&strip[w][l15][k8];
    s16x8 a1 = *(const s16x8*)&strip[w][l15][32 + k8];
    s16x8 a2 = *(const s16x8*)&xwin[myloc][k8];
    s16x8 a3 = *(const s16x8*)&xwin[myloc][32 + k8];
    s16x8 a4 = *(const s16x8*)&strip[w][l15][64 + k8];

    f32x4 accv[4] = {};
    #pragma unroll
    for (int n = 0; n < 4; ++n) {
      const ushort* wr = &w1t[n * 16 + l15][0];
      accv[n] = __builtin_amdgcn_mfma_f32_16x16x32_bf16(a0, *(const s16x8*)&wr[k8],        accv[n], 0, 0, 0);
      accv[n] = __builtin_amdgcn_mfma_f32_16x16x32_bf16(a1, *(const s16x8*)&wr[32 + k8],   accv[n], 0, 0, 0);
      accv[n] = __builtin_amdgcn_mfma_f32_16x16x32_bf16(a2, *(const s16x8*)&wr[64 + k8],   accv[n], 0, 0, 0);
      accv[n] = __builtin_amdgcn_mfma_f32_16x16x32_bf16(a3, *(const s16x8*)&wr[96 + k8],   accv[n], 0, 0, 0);
      accv[n] = __builtin_amdgcn_mfma_f32_16x16x32_bf16(a4, *(const s16x8*)&wr[128 + k8],  accv[n], 0, 0, 0);
    }

    #pragma unroll
    for (int j = 0; j < 4; ++j) {
      const int  locj  = __shfl(recy, lhi * 4 + j) >> 25;
      const bool valid = (eBase + lhi * 4 + j) < end;
      if (valid) {
        #pragma unroll
        for (int n = 0; n < 4; ++n)
          atomicAdd(&acc[locj][n * 16 + l15], relu_f(accv[n][j] + bias[n]));
      }
    }
  }
  __syncthreads();

  // write out acc -> hsum (bf16), coalesced
  #pragma unroll
  for (int i = 0; i < 2; ++i) {
    int c = t + i * 256;
    int r = c >> 4, p = (c & 15) * 4;
    int node = node0 + r;
    if (node < N) {
      f32x4 v = *(const f32x4*)&acc[r][p];
      u32x2 d = { cvtpk(v.x, v.y), cvtpk(v.z, v.w) };
      *(u32x2*)&hsum[(size_t)node * ND + p] = d;
    }
  }
}

// ---- fallback edge kernel (R3, atomic pk_bf16 scatter) ----------------------
__launch_bounds__(256, 3)
__global__ void gc_edge_atomic(const float* __restrict__ x,
                               const int* __restrict__ eidx,
                               const float* __restrict__ eattr,
                               const float* __restrict__ W1e, const float* __restrict__ b1e,
                               ushort* __restrict__ hsum, float* __restrict__ deg,
                               int E, int ngroups) {
  __shared__ ushort   w1t[ND][K1P];
  __shared__ ushort   strip[4][16][K1P];
  __shared__ unsigned hb[4][16][33];

  const int t    = threadIdx.x;
  const int lane = t & 63;
  const int w    = t >> 6;
  const int l15  = lane & 15;
  const int lhi  = lane >> 4;
  const int k8   = lhi * 8;

  for (int i = t; i < K1 * ND; i += 256) w1t[i & 63][i >> 6] = f2bf(W1e[i]);
  __syncthreads();

  float bias[4];
  #pragma unroll
  for (int n = 0; n < 4; ++n) bias[n] = b1e[n * 16 + l15];

  const int el = lane >> 2, part = lane & 3;
  const int wid = blockIdx.x * 4 + w;
  const int nw  = gridDim.x * 4;

  for (int g = wid; g < ngroups; g += nw) {
    const int e0 = g * 16;
    int myidx = 0;
    if (lane < 32)
      myidx = (lane < 16) ? eidx[e0 + lane] : eidx[E + e0 + (lane - 16)];

    const int rrow = __shfl(myidx, el);
    const int rcol = __shfl(myidx, 16 + el);
    const float* xr = x + (size_t)rrow * ND + part * 4;
    const float* xc = x + (size_t)rcol * ND + part * 4;
    const float* ap = eattr + ((size_t)e0 + (lane >> 3)) * DE + (lane & 7) * 4;

    f32x4 vr[4], vc[4], va[2];
    #pragma unroll
    for (int i = 0; i < 4; ++i) vr[i] = *(const f32x4*)(xr + i * 16);
    #pragma unroll
    for (int i = 0; i < 4; ++i) vc[i] = *(const f32x4*)(xc + i * 16);
    va[0] = *(const f32x4*)ap;
    va[1] = *(const f32x4*)(ap + 8 * DE);

    #pragma unroll
    for (int i = 0; i < 4; ++i) {
      u32x2 d = { cvtpk(vr[i].x, vr[i].y), cvtpk(vr[i].z, vr[i].w) };
      *(u32x2*)&strip[w][el][i * 16 + part * 4] = d;
    }
    #pragma unroll
    for (int i = 0; i < 4; ++i) {
      u32x2 d = { cvtpk(vc[i].x, vc[i].y), cvtpk(vc[i].z, vc[i].w) };
      *(u32x2*)&strip[w][el][64 + i * 16 + part * 4] = d;
    }
    #pragma unroll
    for (int i = 0; i < 2; ++i) {
      u32x2 d = { cvtpk(va[i].x, va[i].y), cvtpk(va[i].z, va[i].w) };
      *(u32x2*)&strip[w][(lane >> 3) + i * 8][128 + (lane & 7) * 4] = d;
    }
    asm volatile("s_waitcnt lgkmcnt(0)" ::: "memory");

    f32x4 acc[4] = {};
    #pragma unroll
    for (int ks = 0; ks < 5; ++ks) {
      s16x8 a = *(const s16x8*)&strip[w][l15][ks * 32 + k8];
      #pragma unroll
      for (int n = 0; n < 4; ++n) {
        s16x8 b = *(const s16x8*)&w1t[n * 16 + l15][ks * 32 + k8];
        acc[n] = __builtin_amdgcn_mfma_f32_16x16x32_bf16(a, b, acc[n], 0, 0, 0);
      }
    }

    if (lane >= 16 && lane < 32) atomicAdd(&deg[myidx], 1.0f);

    #pragma unroll
    for (int n = 0; n < 4; ++n) {
      #pragma unroll
      for (int j = 0; j < 4; ++j) {
        float r = relu_f(acc[n][j] + bias[n]);
        float p = __shfl_xor(r, 1);
        if (!(l15 & 1)) hb[w][lhi * 4 + j][(n * 16 + l15) >> 1] = cvtpk(r, p);
      }
    }
    asm volatile("s_waitcnt lgkmcnt(0)" ::: "memory");

    #pragma unroll
    for (int i = 0; i < 8; ++i) {
      int ee = (lane >> 4) + (i >> 1) * 4;
      int q  = (lane & 15) + (i & 1) * 16;
      int sc = __shfl(myidx, 16 + ee);
      uint64_t ad = (uint64_t)((unsigned*)hsum + (size_t)sc * 32 + q);
      unsigned data = hb[w][ee][q];
      asm volatile("global_atomic_pk_add_bf16 %0, %1, off" :: "v"(ad), "v"(data) : "memory");
    }
  }
}

// ---- node kernel: agg = hsum@W2e + deg*b2e; node MLP + residual ------------
__launch_bounds__(256, 2)
__global__ void gc_node(const float* __restrict__ x,
                        const ushort* __restrict__ hsum,
                        const float* __restrict__ deg,
                        const float* __restrict__ W2e, const float* __restrict__ b2e,
                        const float* __restrict__ W1n, const float* __restrict__ b1n,
                        const float* __restrict__ W2n, const float* __restrict__ b2n,
                        float* __restrict__ out, int N) {
  __shared__ ushort w2et[ND][K2P];
  __shared__ ushort w1nt[ND][KNP];
  __shared__ ushort w2nt[ND][K2P];
  __shared__ ushort in_lds[64][KNP];
  __shared__ ushort h_lds[64][K2P];

  const int t    = threadIdx.x;
  const int lane = t & 63;
  const int w    = t >> 6;
  const int l15  = lane & 15;
  const int lhi  = lane >> 4;
  const int k8   = lhi * 8;

  for (int i = t; i < 64 * ND; i += 256) w2et[i & 63][i >> 6] = f2bf(W2e[i]);
  for (int i = t; i < KN * ND; i += 256) w1nt[i & 63][i >> 6] = f2bf(W1n[i]);
  for (int i = t; i < 64 * ND; i += 256) w2nt[i & 63][i >> 6] = f2bf(W2n[i]);

  const int n0 = blockIdx.x * 64;
  #pragma unroll
  for (int i = 0; i < 4; ++i) {
    int chunk = t + i * 256;
    int r = chunk >> 4, p = chunk & 15;
    int node = n0 + r; if (node >= N) node = N - 1;
    f32x4 v = *(const f32x4*)(x + (size_t)node * ND + p * 4);
    unsigned* dst = (unsigned*)&in_lds[r][p * 4];
    dst[0] = cvtpk(v.x, v.y); dst[1] = cvtpk(v.z, v.w);
  }

  const int strip = w * 16;
  {
    int arow = strip + l15;
    int node = n0 + arow; if (node >= N) node = N - 1;
    const s16x8* ph = (const s16x8*)(hsum + (size_t)node * ND);
    s16x8 a0 = ph[lhi];
    s16x8 a1 = ph[4 + lhi];
    __syncthreads();
    f32x4 accg[4] = {};
    #pragma unroll
    for (int n = 0; n < 4; ++n) {
      s16x8 b0 = *(const s16x8*)&w2et[n * 16 + l15][k8];
      s16x8 b1 = *(const s16x8*)&w2et[n * 16 + l15][32 + k8];
      accg[n] = __builtin_amdgcn_mfma_f32_16x16x32_bf16(a0, b0, accg[n], 0, 0, 0);
      accg[n] = __builtin_amdgcn_mfma_f32_16x16x32_bf16(a1, b1, accg[n], 0, 0, 0);
    }
    #pragma unroll
    for (int n = 0; n < 4; ++n) {
      int d = n * 16 + l15;
      float b2 = b2e[d];
      #pragma unroll
      for (int j = 0; j < 4; ++j) {
        int r = strip + lhi * 4 + j;
        int node2 = n0 + r; if (node2 >= N) node2 = N - 1;
        float ag = accg[n][j] + deg[node2] * b2;
        in_lds[r][64 + d] = f2bf(ag);
      }
    }
  }
  __syncthreads();

  const int ar = strip + l15;
  f32x4 acc1[4] = {};
  #pragma unroll
  for (int ks = 0; ks < 4; ++ks) {
    s16x8 a = *(const s16x8*)&in_lds[ar][ks * 32 + k8];
    #pragma unroll
    for (int n = 0; n < 4; ++n) {
      s16x8 b = *(const s16x8*)&w1nt[n * 16 + l15][ks * 32 + k8];
      acc1[n] = __builtin_amdgcn_mfma_f32_16x16x32_bf16(a, b, acc1[n], 0, 0, 0);
    }
  }
  #pragma unroll
  for (int n = 0; n < 4; ++n) {
    int d = n * 16 + l15;
    float bias = b1n[d];
    #pragma unroll
    for (int j = 0; j < 4; ++j)
      h_lds[strip + lhi * 4 + j][d] = f2bf(relu_f(acc1[n][j] + bias));
  }
  __syncthreads();

  f32x4 acc2[4] = {};
  #pragma unroll
  for (int ks = 0; ks < 2; ++ks) {
    s16x8 a = *(const s16x8*)&h_lds[ar][ks * 32 + k8];
    #pragma unroll
    for (int n = 0; n < 4; ++n) {
      s16x8 b = *(const s16x8*)&w2nt[n * 16 + l15][ks * 32 + k8];
      acc2[n] = __builtin_amdgcn_mfma_f32_16x16x32_bf16(a, b, acc2[n], 0, 0, 0);
    }
  }
  #pragma unroll
  for (int n = 0; n < 4; ++n) {
    int d = n * 16 + l15;
    float bias = b2n[d];
    #pragma unroll
    for (int j = 0; j < 4; ++j) {
      int node = n0 + strip + lhi * 4 + j;
      if (node < N) {
        float xv = x[(size_t)node * ND + d];
        out[(size_t)node * ND + d] = relu_f(acc2[n][j] + bias + xv);
      }
    }
  }
}

extern "C" void kernel_launch(void* const* d_in, const int* in_sizes, int n_in,
                              void* d_out, int out_size, void* d_ws, size_t ws_size,
                              hipStream_t stream) {
  const float* x     = (const float*)d_in[0];
  const int*   eidx  = (const int*)d_in[1];
  const float* eattr = (const float*)d_in[2];
  const float* W1e   = (const float*)d_in[3];
  const float* b1e   = (const float*)d_in[4];
  const float* W2e   = (const float*)d_in[5];
  const float* b2e   = (const float*)d_in[6];
  const float* W1n   = (const float*)d_in[7];
  const float* b1n   = (const float*)d_in[8];
  const float* W2n   = (const float*)d_in[9];
  const float* b2n   = (const float*)d_in[10];
  float* out = (float*)d_out;

  const int N  = in_sizes[0] / ND;   // 50000
  const int E  = in_sizes[1] / 2;    // 800000
  const int NB = (N + BKT - 1) / BKT;

  // ws layout
  char* ws = (char*)d_ws;
  ushort* hsum   = (ushort*)ws;                                  // N*ND bf16
  float*  deg    = (float*)(ws + (size_t)N * ND * 2);            // N f32
  size_t  off    = (size_t)N * ND * 2 + (size_t)N * 4;
  int2*   recs   = (int2*)(ws + off);                            // E recs
  int*    offset = (int*)(ws + off + (size_t)E * 8);             // NB+1
  int*    cursor = offset + (NB + 1);                            // NB
  size_t  need   = off + (size_t)E * 8 + (size_t)(2 * NB + 1) * 4;

  if (ws_size >= need) {
    hipMemsetAsync(deg, 0, (size_t)N * 4, stream);
    gc_hist<<<1024, 256, 0, stream>>>(eidx, deg, E);
    gc_prefix<<<1, 256, 0, stream>>>(deg, N, NB, offset, cursor);
    gc_place<<<1024, 256, 0, stream>>>(eidx, cursor, recs, E);
    gc_edge_b<<<NB, 256, 0, stream>>>(x, eattr, W1e, b1e, recs, offset, hsum, N);
  } else {
    hipMemsetAsync(d_ws, 0, (size_t)N * ND * 2 + (size_t)N * 4, stream);
    gc_edge_atomic<<<2048, 256, 0, stream>>>(x, eidx, eattr, W1e, b1e, hsum, deg, E, E / 16);
  }

  int grid_n = (N + 63) / 64;
  gc_node<<<grid_n, 256, 0, stream>>>(x, hsum, deg, W2e, b2e, W1n, b1n, W2n, b2n, out, N);
}

// Round 5
// 252.996 us; speedup vs baseline: 2.2397x; 2.2397x over previous
//
#include <hip/hip_runtime.h>

typedef float    f32x4 __attribute__((ext_vector_type(4)));
typedef short    s16x8 __attribute__((ext_vector_type(8)));
typedef unsigned u32x2 __attribute__((ext_vector_type(2)));
typedef unsigned u32x4 __attribute__((ext_vector_type(4)));

#define ND   64
#define DE   32
#define K1   160
#define K1P  168    // w1t/strip row stride (ushort)
#define K2P  72
#define KN   128
#define KNP  136

__device__ __forceinline__ ushort f2bf(float f) {
  unsigned u = __float_as_uint(f);
  return (ushort)((u + 0x7fffu + ((u >> 16) & 1u)) >> 16);  // RNE
}
__device__ __forceinline__ float bf2f(unsigned u) { return __uint_as_float(u << 16); }
__device__ __forceinline__ float relu_f(float v) { return v > 0.f ? v : 0.f; }
__device__ __forceinline__ unsigned cvtpk(float lo, float hi) {
  unsigned r;
  asm("v_cvt_pk_bf16_f32 %0, %1, %2" : "=v"(r) : "v"(lo), "v"(hi));
  return r;
}

// ---- edge kernel: gather -> GEMM1 -> ReLU -> STREAMING h store (no RMW) ----
__launch_bounds__(256, 3)
__global__ void gc_edge_h(const float* __restrict__ x,
                          const int* __restrict__ eidx,     // [2][E]
                          const float* __restrict__ eattr,  // [E][32]
                          const float* __restrict__ W1e, const float* __restrict__ b1e,
                          ushort* __restrict__ hbuf,        // [E][64] bf16
                          float* __restrict__ deg,
                          int E, int ngroups) {
  __shared__ ushort   w1t[ND][K1P];
  __shared__ ushort   strip[4][16][K1P];
  __shared__ unsigned hb[4][16][36];

  const int t    = threadIdx.x;
  const int lane = t & 63;
  const int w    = t >> 6;
  const int l15  = lane & 15;
  const int lhi  = lane >> 4;
  const int k8   = lhi * 8;

  for (int i = t; i < K1 * ND; i += 256) w1t[i & 63][i >> 6] = f2bf(W1e[i]);
  __syncthreads();

  // hoist all W1e B-fragments into registers (loop-invariant)
  s16x8 bf[4][5];
  #pragma unroll
  for (int n = 0; n < 4; ++n)
    #pragma unroll
    for (int ks = 0; ks < 5; ++ks)
      bf[n][ks] = *(const s16x8*)&w1t[n * 16 + l15][ks * 32 + k8];

  float bias[4];
  #pragma unroll
  for (int n = 0; n < 4; ++n) bias[n] = b1e[n * 16 + l15];

  const int el = lane >> 2, part = lane & 3;
  const int wid = blockIdx.x * 4 + w;
  const int nw  = gridDim.x * 4;

  for (int g = wid; g < ngroups; g += nw) {
    const int e0 = g * 16;
    int myidx = 0;
    if (lane < 32)
      myidx = (lane < 16) ? eidx[e0 + lane] : eidx[E + e0 + (lane - 16)];

    const int rrow = __shfl(myidx, el);
    const int rcol = __shfl(myidx, 16 + el);
    const float* xr = x + (size_t)rrow * ND + part * 4;
    const float* xc = x + (size_t)rcol * ND + part * 4;
    const float* ap = eattr + ((size_t)e0 + (lane >> 3)) * DE + (lane & 7) * 4;

    f32x4 vr[4], vc[4], va[2];
    #pragma unroll
    for (int i = 0; i < 4; ++i) vr[i] = *(const f32x4*)(xr + i * 16);
    #pragma unroll
    for (int i = 0; i < 4; ++i) vc[i] = *(const f32x4*)(xc + i * 16);
    va[0] = *(const f32x4*)ap;
    va[1] = *(const f32x4*)(ap + 8 * DE);

    #pragma unroll
    for (int i = 0; i < 4; ++i) {
      u32x2 d = { cvtpk(vr[i].x, vr[i].y), cvtpk(vr[i].z, vr[i].w) };
      *(u32x2*)&strip[w][el][i * 16 + part * 4] = d;
    }
    #pragma unroll
    for (int i = 0; i < 4; ++i) {
      u32x2 d = { cvtpk(vc[i].x, vc[i].y), cvtpk(vc[i].z, vc[i].w) };
      *(u32x2*)&strip[w][el][64 + i * 16 + part * 4] = d;
    }
    #pragma unroll
    for (int i = 0; i < 2; ++i) {
      u32x2 d = { cvtpk(va[i].x, va[i].y), cvtpk(va[i].z, va[i].w) };
      *(u32x2*)&strip[w][(lane >> 3) + i * 8][128 + (lane & 7) * 4] = d;
    }
    asm volatile("s_waitcnt lgkmcnt(0)" ::: "memory");

    f32x4 acc[4] = {};
    #pragma unroll
    for (int ks = 0; ks < 5; ++ks) {
      s16x8 a = *(const s16x8*)&strip[w][l15][ks * 32 + k8];
      #pragma unroll
      for (int n = 0; n < 4; ++n)
        acc[n] = __builtin_amdgcn_mfma_f32_16x16x32_bf16(a, bf[n][ks], acc[n], 0, 0, 0);
    }

    if (lane >= 16 && lane < 32) atomicAdd(&deg[myidx], 1.0f);

    #pragma unroll
    for (int n = 0; n < 4; ++n) {
      #pragma unroll
      for (int j = 0; j < 4; ++j) {
        float r = relu_f(acc[n][j] + bias[n]);
        float p = __shfl_xor(r, 1);
        if (!(l15 & 1)) hb[w][lhi * 4 + j][(n * 16 + l15) >> 1] = cvtpk(r, p);
      }
    }
    asm volatile("s_waitcnt lgkmcnt(0)" ::: "memory");

    // streaming store: 16 edges x 128B in 2 coalesced dwordx4 per lane
    unsigned* hrow = (unsigned*)hbuf + (size_t)(e0 + (lane >> 2)) * 32 + (lane & 3) * 4;
    u32x4 d0 = *(const u32x4*)&hb[w][lane >> 2][(lane & 3) * 4];
    u32x4 d1 = *(const u32x4*)&hb[w][lane >> 2][(lane & 3) * 4 + 16];
    *(u32x4*)hrow = d0;
    *(u32x4*)(hrow + 16) = d1;
  }
}

// ---- CSR build: prefix over deg (1 block), then place edge ids -------------
__global__ void gc_prefix(const float* __restrict__ deg, int N,
                          int* __restrict__ offset, int* __restrict__ cursor) {
  __shared__ int wt[16], we[16];
  __shared__ int srun, ctot;
  const int t = threadIdx.x, lane = t & 63, w = t >> 6;
  if (t == 0) srun = 0;
  __syncthreads();
  for (int base = 0; base < N; base += 1024) {
    int i = base + t;
    int v = (i < N) ? (int)deg[i] : 0;
    int incl = v;
    #pragma unroll
    for (int d = 1; d < 64; d <<= 1) {
      int u = __shfl_up(incl, d);
      if (lane >= d) incl += u;
    }
    if (lane == 63) wt[w] = incl;
    __syncthreads();
    if (t == 0) {
      int run = 0;
      #pragma unroll
      for (int k = 0; k < 16; ++k) { we[k] = run; run += wt[k]; }
      ctot = run;
    }
    __syncthreads();
    if (i < N) {
      int ex = srun + we[w] + incl - v;
      offset[i] = ex; cursor[i] = ex;
    }
    __syncthreads();
    if (t == 0) srun += ctot;
    __syncthreads();
  }
  if (t == 0) offset[N] = srun;
}

__global__ void gc_place(const int* __restrict__ eidx, int* __restrict__ cursor,
                         int* __restrict__ recs, int E) {
  int i = blockIdx.x * blockDim.x + threadIdx.x;
  for (; i < E; i += gridDim.x * blockDim.x) {
    int col = eidx[E + i];
    int pos = atomicAdd(&cursor[col], 1);
    recs[pos] = i;
  }
}

// ---- aggregation: one wave per node, gather hbuf rows, reduce, write -------
__launch_bounds__(256, 8)
__global__ void gc_agg(const ushort* __restrict__ hbuf,
                       const int* __restrict__ recs,
                       const int* __restrict__ offset,
                       ushort* __restrict__ hsum, int N) {
  const int t = threadIdx.x, lane = t & 63, w = t >> 6;
  const int v = blockIdx.x * 4 + w;
  if (v >= N) return;
  const int g = lane >> 4, l15 = lane & 15;
  const int start = offset[v], end = offset[v + 1];

  float a0 = 0.f, a1 = 0.f, a2 = 0.f, a3 = 0.f;
  for (int c = start; c < end; c += 4) {
    int idx = c + g;
    if (idx < end) {
      int eid = recs[idx];
      u32x2 d = *(const u32x2*)(hbuf + (size_t)eid * ND + l15 * 4);
      a0 += bf2f(d.x & 0xffffu); a1 += bf2f(d.x >> 16);
      a2 += bf2f(d.y & 0xffffu); a3 += bf2f(d.y >> 16);
    }
  }
  a0 += __shfl_xor(a0, 16); a1 += __shfl_xor(a1, 16);
  a2 += __shfl_xor(a2, 16); a3 += __shfl_xor(a3, 16);
  a0 += __shfl_xor(a0, 32); a1 += __shfl_xor(a1, 32);
  a2 += __shfl_xor(a2, 32); a3 += __shfl_xor(a3, 32);
  if (lane < 16) {
    u32x2 o = { cvtpk(a0, a1), cvtpk(a2, a3) };
    *(u32x2*)&hsum[(size_t)v * ND + l15 * 4] = o;
  }
}

// ---- fallback edge kernel (R3, atomic pk_bf16 scatter) ---------------------
__launch_bounds__(256, 3)
__global__ void gc_edge_atomic(const float* __restrict__ x,
                               const int* __restrict__ eidx,
                               const float* __restrict__ eattr,
                               const float* __restrict__ W1e, const float* __restrict__ b1e,
                               ushort* __restrict__ hsum, float* __restrict__ deg,
                               int E, int ngroups) {
  __shared__ ushort   w1t[ND][K1P];
  __shared__ ushort   strip[4][16][K1P];
  __shared__ unsigned hb[4][16][33];

  const int t    = threadIdx.x;
  const int lane = t & 63;
  const int w    = t >> 6;
  const int l15  = lane & 15;
  const int lhi  = lane >> 4;
  const int k8   = lhi * 8;

  for (int i = t; i < K1 * ND; i += 256) w1t[i & 63][i >> 6] = f2bf(W1e[i]);
  __syncthreads();

  float bias[4];
  #pragma unroll
  for (int n = 0; n < 4; ++n) bias[n] = b1e[n * 16 + l15];

  const int el = lane >> 2, part = lane & 3;
  const int wid = blockIdx.x * 4 + w;
  const int nw  = gridDim.x * 4;

  for (int g = wid; g < ngroups; g += nw) {
    const int e0 = g * 16;
    int myidx = 0;
    if (lane < 32)
      myidx = (lane < 16) ? eidx[e0 + lane] : eidx[E + e0 + (lane - 16)];

    const int rrow = __shfl(myidx, el);
    const int rcol = __shfl(myidx, 16 + el);
    const float* xr = x + (size_t)rrow * ND + part * 4;
    const float* xc = x + (size_t)rcol * ND + part * 4;
    const float* ap = eattr + ((size_t)e0 + (lane >> 3)) * DE + (lane & 7) * 4;

    f32x4 vr[4], vc[4], va[2];
    #pragma unroll
    for (int i = 0; i < 4; ++i) vr[i] = *(const f32x4*)(xr + i * 16);
    #pragma unroll
    for (int i = 0; i < 4; ++i) vc[i] = *(const f32x4*)(xc + i * 16);
    va[0] = *(const f32x4*)ap;
    va[1] = *(const f32x4*)(ap + 8 * DE);

    #pragma unroll
    for (int i = 0; i < 4; ++i) {
      u32x2 d = { cvtpk(vr[i].x, vr[i].y), cvtpk(vr[i].z, vr[i].w) };
      *(u32x2*)&strip[w][el][i * 16 + part * 4] = d;
    }
    #pragma unroll
    for (int i = 0; i < 4; ++i) {
      u32x2 d = { cvtpk(vc[i].x, vc[i].y), cvtpk(vc[i].z, vc[i].w) };
      *(u32x2*)&strip[w][el][64 + i * 16 + part * 4] = d;
    }
    #pragma unroll
    for (int i = 0; i < 2; ++i) {
      u32x2 d = { cvtpk(va[i].x, va[i].y), cvtpk(va[i].z, va[i].w) };
      *(u32x2*)&strip[w][(lane >> 3) + i * 8][128 + (lane & 7) * 4] = d;
    }
    asm volatile("s_waitcnt lgkmcnt(0)" ::: "memory");

    f32x4 acc[4] = {};
    #pragma unroll
    for (int ks = 0; ks < 5; ++ks) {
      s16x8 a = *(const s16x8*)&strip[w][l15][ks * 32 + k8];
      #pragma unroll
      for (int n = 0; n < 4; ++n) {
        s16x8 b = *(const s16x8*)&w1t[n * 16 + l15][ks * 32 + k8];
        acc[n] = __builtin_amdgcn_mfma_f32_16x16x32_bf16(a, b, acc[n], 0, 0, 0);
      }
    }

    if (lane >= 16 && lane < 32) atomicAdd(&deg[myidx], 1.0f);

    #pragma unroll
    for (int n = 0; n < 4; ++n) {
      #pragma unroll
      for (int j = 0; j < 4; ++j) {
        float r = relu_f(acc[n][j] + bias[n]);
        float p = __shfl_xor(r, 1);
        if (!(l15 & 1)) hb[w][lhi * 4 + j][(n * 16 + l15) >> 1] = cvtpk(r, p);
      }
    }
    asm volatile("s_waitcnt lgkmcnt(0)" ::: "memory");

    #pragma unroll
    for (int i = 0; i < 8; ++i) {
      int ee = (lane >> 4) + (i >> 1) * 4;
      int q  = (lane & 15) + (i & 1) * 16;
      int sc = __shfl(myidx, 16 + ee);
      uint64_t ad = (uint64_t)((unsigned*)hsum + (size_t)sc * 32 + q);
      unsigned data = hb[w][ee][q];
      asm volatile("global_atomic_pk_add_bf16 %0, %1, off" :: "v"(ad), "v"(data) : "memory");
    }
  }
}

// ---- node kernel: agg = hsum@W2e + deg*b2e; node MLP + residual ------------
__launch_bounds__(256, 2)
__global__ void gc_node(const float* __restrict__ x,
                        const ushort* __restrict__ hsum,
                        const float* __restrict__ deg,
                        const float* __restrict__ W2e, const float* __restrict__ b2e,
                        const float* __restrict__ W1n, const float* __restrict__ b1n,
                        const float* __restrict__ W2n, const float* __restrict__ b2n,
                        float* __restrict__ out, int N) {
  __shared__ ushort w2et[ND][K2P];
  __shared__ ushort w1nt[ND][KNP];
  __shared__ ushort w2nt[ND][K2P];
  __shared__ ushort in_lds[64][KNP];
  __shared__ ushort h_lds[64][K2P];

  const int t    = threadIdx.x;
  const int lane = t & 63;
  const int w    = t >> 6;
  const int l15  = lane & 15;
  const int lhi  = lane >> 4;
  const int k8   = lhi * 8;

  for (int i = t; i < 64 * ND; i += 256) w2et[i & 63][i >> 6] = f2bf(W2e[i]);
  for (int i = t; i < KN * ND; i += 256) w1nt[i & 63][i >> 6] = f2bf(W1n[i]);
  for (int i = t; i < 64 * ND; i += 256) w2nt[i & 63][i >> 6] = f2bf(W2n[i]);

  const int n0 = blockIdx.x * 64;
  #pragma unroll
  for (int i = 0; i < 4; ++i) {
    int chunk = t + i * 256;
    int r = chunk >> 4, p = chunk & 15;
    int node = n0 + r; if (node >= N) node = N - 1;
    f32x4 v = *(const f32x4*)(x + (size_t)node * ND + p * 4);
    unsigned* dst = (unsigned*)&in_lds[r][p * 4];
    dst[0] = cvtpk(v.x, v.y); dst[1] = cvtpk(v.z, v.w);
  }

  const int strip = w * 16;
  {
    int arow = strip + l15;
    int node = n0 + arow; if (node >= N) node = N - 1;
    const s16x8* ph = (const s16x8*)(hsum + (size_t)node * ND);
    s16x8 a0 = ph[lhi];
    s16x8 a1 = ph[4 + lhi];
    __syncthreads();
    f32x4 accg[4] = {};
    #pragma unroll
    for (int n = 0; n < 4; ++n) {
      s16x8 b0 = *(const s16x8*)&w2et[n * 16 + l15][k8];
      s16x8 b1 = *(const s16x8*)&w2et[n * 16 + l15][32 + k8];
      accg[n] = __builtin_amdgcn_mfma_f32_16x16x32_bf16(a0, b0, accg[n], 0, 0, 0);
      accg[n] = __builtin_amdgcn_mfma_f32_16x16x32_bf16(a1, b1, accg[n], 0, 0, 0);
    }
    #pragma unroll
    for (int n = 0; n < 4; ++n) {
      int d = n * 16 + l15;
      float b2 = b2e[d];
      #pragma unroll
      for (int j = 0; j < 4; ++j) {
        int r = strip + lhi * 4 + j;
        int node2 = n0 + r; if (node2 >= N) node2 = N - 1;
        float ag = accg[n][j] + deg[node2] * b2;
        in_lds[r][64 + d] = f2bf(ag);
      }
    }
  }
  __syncthreads();

  const int ar = strip + l15;
  f32x4 acc1[4] = {};
  #pragma unroll
  for (int ks = 0; ks < 4; ++ks) {
    s16x8 a = *(const s16x8*)&in_lds[ar][ks * 32 + k8];
    #pragma unroll
    for (int n = 0; n < 4; ++n) {
      s16x8 b = *(const s16x8*)&w1nt[n * 16 + l15][ks * 32 + k8];
      acc1[n] = __builtin_amdgcn_mfma_f32_16x16x32_bf16(a, b, acc1[n], 0, 0, 0);
    }
  }
  #pragma unroll
  for (int n = 0; n < 4; ++n) {
    int d = n * 16 + l15;
    float bias = b1n[d];
    #pragma unroll
    for (int j = 0; j < 4; ++j)
      h_lds[strip + lhi * 4 + j][d] = f2bf(relu_f(acc1[n][j] + bias));
  }
  __syncthreads();

  f32x4 acc2[4] = {};
  #pragma unroll
  for (int ks = 0; ks < 2; ++ks) {
    s16x8 a = *(const s16x8*)&h_lds[ar][ks * 32 + k8];
    #pragma unroll
    for (int n = 0; n < 4; ++n) {
      s16x8 b = *(const s16x8*)&w2nt[n * 16 + l15][ks * 32 + k8];
      acc2[n] = __builtin_amdgcn_mfma_f32_16x16x32_bf16(a, b, acc2[n], 0, 0, 0);
    }
  }
  #pragma unroll
  for (int n = 0; n < 4; ++n) {
    int d = n * 16 + l15;
    float bias = b2n[d];
    #pragma unroll
    for (int j = 0; j < 4; ++j) {
      int node = n0 + strip + lhi * 4 + j;
      if (node < N) {
        float xv = x[(size_t)node * ND + d];
        out[(size_t)node * ND + d] = relu_f(acc2[n][j] + bias + xv);
      }
    }
  }
}

extern "C" void kernel_launch(void* const* d_in, const int* in_sizes, int n_in,
                              void* d_out, int out_size, void* d_ws, size_t ws_size,
                              hipStream_t stream) {
  const float* x     = (const float*)d_in[0];
  const int*   eidx  = (const int*)d_in[1];
  const float* eattr = (const float*)d_in[2];
  const float* W1e   = (const float*)d_in[3];
  const float* b1e   = (const float*)d_in[4];
  const float* W2e   = (const float*)d_in[5];
  const float* b2e   = (const float*)d_in[6];
  const float* W1n   = (const float*)d_in[7];
  const float* b1n   = (const float*)d_in[8];
  const float* W2n   = (const float*)d_in[9];
  const float* b2n   = (const float*)d_in[10];
  float* out = (float*)d_out;

  const int N = in_sizes[0] / ND;   // 50000
  const int E = in_sizes[1] / 2;    // 800000

  char* ws = (char*)d_ws;
  // full-path layout
  ushort* hbuf   = (ushort*)ws;                                   // E*ND bf16
  ushort* hsum   = (ushort*)(ws + (size_t)E * ND * 2);            // N*ND bf16
  float*  deg    = (float*)(ws + (size_t)E * ND * 2 + (size_t)N * ND * 2);
  int*    offset = (int*)((char*)deg + (size_t)N * 4);            // N+1
  int*    cursor = offset + (N + 1);                              // N
  int*    recs   = cursor + N;                                    // E
  size_t need = (size_t)E * ND * 2 + (size_t)N * ND * 2 + (size_t)N * 4
              + (size_t)(2 * N + 1) * 4 + (size_t)E * 4;

  if (ws_size >= need) {
    hipMemsetAsync(deg, 0, (size_t)N * 4, stream);
    gc_edge_h<<<2048, 256, 0, stream>>>(x, eidx, eattr, W1e, b1e, hbuf, deg, E, E / 16);
    gc_prefix<<<1, 1024, 0, stream>>>(deg, N, offset, cursor);
    gc_place<<<1024, 256, 0, stream>>>(eidx, cursor, recs, E);
    gc_agg<<<(N + 3) / 4, 256, 0, stream>>>(hbuf, recs, offset, hsum, N);
    gc_node<<<(N + 63) / 64, 256, 0, stream>>>(x, hsum, deg, W2e, b2e, W1n, b1n, W2n, b2n, out, N);
  } else {
    ushort* hsum_fb = (ushort*)ws;
    float*  deg_fb  = (float*)(ws + (size_t)N * ND * 2);
    hipMemsetAsync(ws, 0, (size_t)N * ND * 2 + (size_t)N * 4, stream);
    gc_edge_atomic<<<2048, 256, 0, stream>>>(x, eidx, eattr, W1e, b1e, hsum_fb, deg_fb, E, E / 16);
    gc_node<<<(N + 63) / 64, 256, 0, stream>>>(x, hsum_fb, deg_fb, W2e, b2e, W1n, b1n, W2n, b2n, out, N);
  }
}